// Round 2
// baseline (2733.534 us; speedup 1.0000x reference)
//
#include <hip/hip_runtime.h>
#include <math.h>

// Problem constants (from setup_inputs)
#define NN 100000            // nodes
#define NE 1600000           // real edges
#define ET (NE + NN)         // edges + self loops = 1,700,000
#define FIN 128
#define H1 4
#define C1 8
#define F1 32                // H1*C1
#define FOUT 16
#define NSLOPE 0.2f
#define NB_SCAN ((NN + 255) / 256)   // 391
#define NPART 8
#define PARTW (NN / NPART)           // 12500 nodes per dst-partition

// ---------------- CSR build ----------------

__global__ __launch_bounds__(256) void k_count(const int* __restrict__ dstA, int* __restrict__ deg) {
    int e = blockIdx.x * 256 + threadIdx.x;
    if (e < NE) atomicAdd(&deg[dstA[e]], 1);
}

__global__ __launch_bounds__(256) void k_scan_a(const int* __restrict__ deg, int* __restrict__ bsum) {
    __shared__ int s[256];
    int t = threadIdx.x;
    int n = blockIdx.x * 256 + t;
    int v = (n < NN) ? deg[n] + 1 : 0;   // +1: self loop
    s[t] = v; __syncthreads();
    for (int off = 128; off > 0; off >>= 1) {
        if (t < off) s[t] += s[t + off];
        __syncthreads();
    }
    if (t == 0) bsum[blockIdx.x] = s[0];
}

__global__ __launch_bounds__(512) void k_scan_b(const int* __restrict__ bsum, int* __restrict__ boff) {
    __shared__ int s[512];
    int t = threadIdx.x;
    int v = (t < NB_SCAN) ? bsum[t] : 0;
    s[t] = v; __syncthreads();
    for (int off = 1; off < 512; off <<= 1) {
        int xv = (t >= off) ? s[t - off] : 0;
        __syncthreads();
        s[t] += xv;
        __syncthreads();
    }
    if (t < NB_SCAN) boff[t] = s[t] - v;  // exclusive
}

__global__ __launch_bounds__(256) void k_scan_c(const int* __restrict__ deg, const int* __restrict__ boff,
                                                int* __restrict__ rowstart, int* __restrict__ cursor) {
    __shared__ int s[256];
    int t = threadIdx.x;
    int n = blockIdx.x * 256 + t;
    int v = (n < NN) ? deg[n] + 1 : 0;
    s[t] = v; __syncthreads();
    for (int off = 1; off < 256; off <<= 1) {
        int xv = (t >= off) ? s[t - off] : 0;
        __syncthreads();
        s[t] += xv;
        __syncthreads();
    }
    int incl = s[t];
    int excl = incl - v;
    int base = boff[blockIdx.x];
    if (n < NN) { rowstart[n] = base + excl; cursor[n] = base + excl; }
    if (n == NN - 1) rowstart[NN] = base + incl;  // == ET
}

__global__ __launch_bounds__(64) void k_binit(const int* __restrict__ rowstart, int* __restrict__ bcur) {
    int t = threadIdx.x;
    if (t < NPART) bcur[t] = rowstart[t * PARTW];
}

// Phase 1: wave-aggregated append of (src,dst) pairs into dst-partition-contiguous
// regions of `pairs`. Coalesced writes (per-wave contiguous chunks per partition).
__global__ __launch_bounds__(256) void k_bucket(const int* __restrict__ srcA, const int* __restrict__ dstA,
                                                int* __restrict__ bcur, int2* __restrict__ pairs) {
    int e = blockIdx.x * 256 + threadIdx.x;
    if (e >= ET) return;
    int s, d;
    if (e < NE) { s = srcA[e]; d = dstA[e]; }
    else        { s = e - NE;  d = s; }        // self loop
    int p = d / PARTW;
    int lane = threadIdx.x & 63;
    unsigned long long lanebit = 1ULL << lane;
#pragma unroll
    for (int q = 0; q < NPART; q++) {
        unsigned long long m = __ballot(p == q);
        if (m == 0) continue;
        if (p == q) {
            int leader = __ffsll((long long)m) - 1;
            int base = 0;
            if (lane == leader) base = atomicAdd(&bcur[q], __popcll(m));
            base = __shfl(base, leader);
            int off = __popcll(m & (lanebit - 1));
            pairs[base + off] = make_int2(s, d);
        }
    }
}

// Phase 2: pairs are partition-ordered; linear block order => writes to esrc are
// time-localized within an ~850KB window => full-line merging in L2.
__global__ __launch_bounds__(256) void k_scatter2(const int2* __restrict__ pairs,
                                                  int* __restrict__ cursor, int* __restrict__ esrc) {
    int e = blockIdx.x * 256 + threadIdx.x;
    if (e >= ET) return;
    int2 pr = pairs[e];
    int pos = atomicAdd(&cursor[pr.y], 1);
    esrc[pos] = pr.x;
}

// ---------------- Layer 1: x@W1 + attention coefficients ----------------

__global__ __launch_bounds__(256) void k_gemm1(const float* __restrict__ x, const float* __restrict__ W1,
        const float* __restrict__ a1s, const float* __restrict__ a1d,
        float* __restrict__ xw1, float* __restrict__ as1, float* __restrict__ ad1) {
    int n = blockIdx.x * 256 + threadIdx.x;
    if (n >= NN) return;
    float acc[F1];
#pragma unroll
    for (int c = 0; c < F1; c++) acc[c] = 0.f;
    const float4* x4 = (const float4*)(x + (size_t)n * FIN);
#pragma unroll 4
    for (int k4 = 0; k4 < FIN / 4; k4++) {
        float4 xv = x4[k4];
        float xk[4] = {xv.x, xv.y, xv.z, xv.w};
#pragma unroll
        for (int kk = 0; kk < 4; kk++) {
            int k = k4 * 4 + kk;
#pragma unroll
            for (int c = 0; c < F1; c++)
                acc[c] = fmaf(xk[kk], W1[k * F1 + c], acc[c]);  // W1 addr wave-uniform -> s_load
        }
    }
    float4* o4 = (float4*)(xw1 + (size_t)n * F1);
#pragma unroll
    for (int c4 = 0; c4 < F1 / 4; c4++)
        o4[c4] = make_float4(acc[c4*4], acc[c4*4+1], acc[c4*4+2], acc[c4*4+3]);
#pragma unroll
    for (int h = 0; h < H1; h++) {
        float ss = 0.f, dd = 0.f;
#pragma unroll
        for (int c = 0; c < C1; c++) {
            ss = fmaf(acc[h*C1+c], a1s[h*C1+c], ss);
            dd = fmaf(acc[h*C1+c], a1d[h*C1+c], dd);
        }
        as1[n*H1+h] = ss;
        ad1[n*H1+h] = dd;
    }
}

// ---------------- Layer 1: gather softmax-aggregate + bias + ELU ----------------
// 32 lanes per node (8 nodes / 256-block); lane owns channel c, head h=c>>3.
// Softmax without max-subtraction: alpha = exp(e)/sum(exp(e)) (no overflow, |e|<~10).

__global__ __launch_bounds__(256) void k_gather1(const int* __restrict__ rowstart, const int* __restrict__ esrc,
        const float* __restrict__ as1, const float* __restrict__ ad1,
        const float* __restrict__ xw1, const float* __restrict__ b1,
        float* __restrict__ h1) {
    int n = blockIdx.x * 8 + (threadIdx.x >> 5);
    if (n >= NN) return;
    int c = threadIdx.x & 31;
    int h = c >> 3;
    float adh = ad1[n * H1 + h];
    int beg = rowstart[n], end = rowstart[n + 1];
    float accn = 0.f, accd = 0.f;
    for (int i = beg; i < end; i++) {
        int s = esrc[i];
        float e = as1[s * H1 + h] + adh;
        e = (e > 0.f) ? e : NSLOPE * e;
        float ee = __expf(e);
        accd += ee;
        accn = fmaf(ee, xw1[(size_t)s * F1 + c], accn);
    }
    float y = accn / accd + b1[c];
    y = (y > 0.f) ? y : expm1f(y);   // ELU
    h1[(size_t)n * F1 + c] = y;
}

// ---------------- Layer 2: h1@W2 + attention coefficients ----------------

__global__ __launch_bounds__(256) void k_node2(const float* __restrict__ h1, const float* __restrict__ W2,
        const float* __restrict__ a2s, const float* __restrict__ a2d,
        float* __restrict__ xw2, float* __restrict__ as2, float* __restrict__ ad2) {
    int n = blockIdx.x * 256 + threadIdx.x;
    if (n >= NN) return;
    float acc[FOUT];
#pragma unroll
    for (int j = 0; j < FOUT; j++) acc[j] = 0.f;
    const float4* h4 = (const float4*)(h1 + (size_t)n * F1);
#pragma unroll
    for (int i4 = 0; i4 < F1 / 4; i4++) {
        float4 hv = h4[i4];
        float hk[4] = {hv.x, hv.y, hv.z, hv.w};
#pragma unroll
        for (int kk = 0; kk < 4; kk++) {
            int i = i4 * 4 + kk;
#pragma unroll
            for (int j = 0; j < FOUT; j++)
                acc[j] = fmaf(hk[kk], W2[i * FOUT + j], acc[j]);
        }
    }
    float ss = 0.f, dd = 0.f;
#pragma unroll
    for (int j = 0; j < FOUT; j++) {
        ss = fmaf(acc[j], a2s[j], ss);
        dd = fmaf(acc[j], a2d[j], dd);
    }
    float4* o4 = (float4*)(xw2 + (size_t)n * FOUT);
#pragma unroll
    for (int j4 = 0; j4 < FOUT / 4; j4++)
        o4[j4] = make_float4(acc[j4*4], acc[j4*4+1], acc[j4*4+2], acc[j4*4+3]);
    as2[n] = ss;
    ad2[n] = dd;
}

// ---------------- Layer 2: gather softmax-aggregate + bias + log_softmax ----------------
// 16 lanes per node (16 nodes / 256-block); lane owns output class c.

__global__ __launch_bounds__(256) void k_gather2(const int* __restrict__ rowstart, const int* __restrict__ esrc,
        const float* __restrict__ as2, const float* __restrict__ ad2,
        const float* __restrict__ xw2, const float* __restrict__ b2,
        float* __restrict__ out) {
    int n = blockIdx.x * 16 + (threadIdx.x >> 4);
    if (n >= NN) return;
    int c = threadIdx.x & 15;
    float adn = ad2[n];
    int beg = rowstart[n], end = rowstart[n + 1];
    float accn = 0.f, accd = 0.f;
    for (int i = beg; i < end; i++) {
        int s = esrc[i];
        float e = as2[s] + adn;
        e = (e > 0.f) ? e : NSLOPE * e;
        float ee = __expf(e);
        accd += ee;
        accn = fmaf(ee, xw2[(size_t)s * FOUT + c], accn);
    }
    float y = accn / accd + b2[c];
    // log_softmax across the 16 lanes of this node group
    float m = y;
#pragma unroll
    for (int off = 8; off > 0; off >>= 1) m = fmaxf(m, __shfl_xor(m, off));
    float ex = __expf(y - m);
    float sum = ex;
#pragma unroll
    for (int off = 8; off > 0; off >>= 1) sum += __shfl_xor(sum, off);
    out[(size_t)n * FOUT + c] = y - m - logf(sum);
}

// ---------------- launch ----------------

extern "C" void kernel_launch(void* const* d_in, const int* in_sizes, int n_in,
                              void* d_out, int out_size, void* d_ws, size_t ws_size,
                              hipStream_t stream) {
    const float* x   = (const float*)d_in[0];
    const int*   ei  = (const int*)d_in[1];
    const float* W1  = (const float*)d_in[2];
    const float* a1s = (const float*)d_in[3];
    const float* a1d = (const float*)d_in[4];
    const float* b1  = (const float*)d_in[5];
    const float* W2  = (const float*)d_in[6];
    const float* a2s = (const float*)d_in[7];
    const float* a2d = (const float*)d_in[8];
    const float* b2  = (const float*)d_in[9];
    float* out = (float*)d_out;

    const int* srcA = ei;        // edge_index[0]
    const int* dstA = ei + NE;   // edge_index[1]

    char* w = (char*)d_ws;
    size_t off = 0;
    auto carve = [&](size_t bytes) -> void* {
        void* p = w + off;
        off = (off + bytes + 255) & ~(size_t)255;
        return p;
    };
    float* xw1     = (float*)carve((size_t)NN * F1 * 4);     // 12.8 MB
    float* as1     = (float*)carve((size_t)NN * H1 * 4);
    float* ad1     = (float*)carve((size_t)NN * H1 * 4);
    // h1..ad2 form a 20MB block; `pairs` (13.6MB) aliases it — pairs is dead
    // before gather1 writes h1 (stream-ordered), so this is safe.
    size_t h1_off  = off;
    float* h1      = (float*)carve((size_t)NN * F1 * 4);     // 12.8 MB
    float* xw2     = (float*)carve((size_t)NN * FOUT * 4);   // 6.4 MB
    float* as2     = (float*)carve((size_t)NN * 4);
    float* ad2     = (float*)carve((size_t)NN * 4);
    int2*  pairs   = (int2*)(w + h1_off);                    // alias
    int* deg       = (int*)carve((size_t)NN * 4);
    int* rowstart  = (int*)carve((size_t)(NN + 1) * 4);
    int* cursor    = (int*)carve((size_t)NN * 4);
    int* esrc      = (int*)carve((size_t)ET * 4);            // 6.8 MB
    int* bsum      = (int*)carve((size_t)NB_SCAN * 4);
    int* boff      = (int*)carve((size_t)NB_SCAN * 4);
    int* bcur      = (int*)carve((size_t)NPART * 4);
    (void)ws_size; (void)in_sizes; (void)n_in; (void)out_size;

    hipMemsetAsync(deg, 0, (size_t)NN * 4, stream);

    k_count   <<<(NE + 255) / 256, 256, 0, stream>>>(dstA, deg);
    k_scan_a  <<<NB_SCAN, 256, 0, stream>>>(deg, bsum);
    k_scan_b  <<<1, 512, 0, stream>>>(bsum, boff);
    k_scan_c  <<<NB_SCAN, 256, 0, stream>>>(deg, boff, rowstart, cursor);
    k_binit   <<<1, 64, 0, stream>>>(rowstart, bcur);
    k_bucket  <<<(ET + 255) / 256, 256, 0, stream>>>(srcA, dstA, bcur, pairs);
    k_scatter2<<<(ET + 255) / 256, 256, 0, stream>>>(pairs, cursor, esrc);

    k_gemm1  <<<(NN + 255) / 256, 256, 0, stream>>>(x, W1, a1s, a1d, xw1, as1, ad1);
    k_gather1<<<(NN + 7) / 8, 256, 0, stream>>>(rowstart, esrc, as1, ad1, xw1, b1, h1);
    k_node2  <<<(NN + 255) / 256, 256, 0, stream>>>(h1, W2, a2s, a2d, xw2, as2, ad2);
    k_gather2<<<(NN + 15) / 16, 256, 0, stream>>>(rowstart, esrc, as2, ad2, xw2, b2, out);
}

// Round 3
// 366.315 us; speedup vs baseline: 7.4622x; 7.4622x over previous
//
#include <hip/hip_runtime.h>
#include <math.h>

// Problem constants (from setup_inputs)
#define NN 100000            // nodes
#define NE 1600000           // real edges
#define ET (NE + NN)         // edges + self loops = 1,700,000
#define FIN 128
#define H1 4
#define C1 8
#define F1 32                // H1*C1
#define FOUT 16
#define NSLOPE 0.2f

// Radix-partition parameters (CSR build, zero global atomics)
#define PARTW 512                          // nodes per dst-partition
#define NPART ((NN + PARTW - 1) / PARTW)   // 196
#define CHUNK 8192                         // edges per hist/part block
#define NBLK ((ET + CHUNK - 1) / CHUNK)    // 208
#define MTOT (NPART * NBLK)                // 40768 scan entries

// ---------------- wave/block scan helpers ----------------

__device__ inline int wave_incl_scan(int v) {
#pragma unroll
    for (int off = 1; off < 64; off <<= 1) {
        int u = __shfl_up(v, off);
        if ((threadIdx.x & 63) >= off) v += u;
    }
    return v;
}

// ---------------- CSR build: 3-pass radix partition + per-partition sort ----------------

// Pass 1: per-block LDS histogram over 196 dst-partitions.
__global__ __launch_bounds__(256) void k_hist(const int* __restrict__ dstA, int* __restrict__ bh) {
    __shared__ int h[NPART];
    int t = threadIdx.x;
    for (int i = t; i < NPART; i += 256) h[i] = 0;
    __syncthreads();
    int base = blockIdx.x * CHUNK;
#pragma unroll
    for (int k = 0; k < CHUNK / 256; k++) {
        int e = base + k * 256 + t;
        if (e < ET) {
            int d = (e < NE) ? dstA[e] : (e - NE);   // virtual self-loop edges
            atomicAdd(&h[d >> 9], 1);
        }
    }
    __syncthreads();
    for (int i = t; i < NPART; i += 256) bh[i * NBLK + blockIdx.x] = h[i];  // column-major
}

// Pass 2: single-block exclusive scan of bh[MTOT] (in place), wave-shuffle based.
__global__ __launch_bounds__(1024) void k_pscan(int* __restrict__ bh, int* __restrict__ rowstart) {
    __shared__ int wsum[16];
    int t = threadIdx.x;
    int wid = t >> 6, lane = t & 63;
    int carry = 0;                       // per-thread (all threads agree)
    for (int it = 0; it < (MTOT + 1023) / 1024; it++) {
        int idx = it * 1024 + t;
        int v = (idx < MTOT) ? bh[idx] : 0;
        int incl = wave_incl_scan(v);
        if (lane == 63) wsum[wid] = incl;
        __syncthreads();
        if (wid == 0) {
            int wv = (lane < 16) ? wsum[lane] : 0;
            wv = wave_incl_scan(wv);
            if (lane < 16) wsum[lane] = wv;
        }
        __syncthreads();
        int blockincl = incl + (wid ? wsum[wid - 1] : 0);
        int total = wsum[15];
        if (idx < MTOT) bh[idx] = carry + blockincl - v;  // exclusive
        carry += total;
        __syncthreads();                  // protect wsum for next iteration
    }
    if (t == 0) rowstart[NN] = ET;
}

// Pass 3: scatter (src,dst) into partition-ordered pairs buffer. LDS cursors
// seeded from the scan -> every edge has a pre-reserved slot; NO global atomics.
__global__ __launch_bounds__(256) void k_part(const int* __restrict__ srcA, const int* __restrict__ dstA,
                                              const int* __restrict__ bh, int2* __restrict__ pairs) {
    __shared__ int cur[NPART];
    int t = threadIdx.x;
    for (int i = t; i < NPART; i += 256) cur[i] = bh[i * NBLK + blockIdx.x];
    __syncthreads();
    int base = blockIdx.x * CHUNK;
#pragma unroll
    for (int k = 0; k < CHUNK / 256; k++) {
        int e = base + k * 256 + t;
        if (e < ET) {
            int s, d;
            if (e < NE) { s = srcA[e]; d = dstA[e]; }
            else        { s = e - NE;  d = s; }
            int pos = atomicAdd(&cur[d >> 9], 1);   // LDS atomic
            pairs[pos] = make_int2(s, d);
        }
    }
}

// Pass 4: one block per partition: LDS counting sort of <=512 local nodes.
// Emits rowstart (replacing the old count+scan kernels) and esrc.
__global__ __launch_bounds__(1024) void k_sort(const int* __restrict__ bh, const int2* __restrict__ pairs,
                                               int* __restrict__ rowstart, int* __restrict__ esrc) {
    __shared__ int hist[PARTW];
    __shared__ int sa[PARTW], sb[PARTW];
    int p = blockIdx.x;
    int t = threadIdx.x;
    int n0 = p << 9;
    int nn = min(PARTW, NN - n0);
    int base = bh[p * NBLK];
    int endp = (p == NPART - 1) ? ET : bh[(p + 1) * NBLK];
    int cnt = endp - base;
    if (t < PARTW) hist[t] = 0;
    __syncthreads();
    for (int i = t; i < cnt; i += 1024)
        atomicAdd(&hist[pairs[base + i].y - n0], 1);
    __syncthreads();
    // exclusive scan of hist via Hillis-Steele ping-pong (512 lanes active)
    if (t < PARTW) sa[t] = hist[t];
    __syncthreads();
    int* pin = sa; int* pout = sb;
    for (int off = 1; off < PARTW; off <<= 1) {
        if (t < PARTW) pout[t] = pin[t] + ((t >= off) ? pin[t - off] : 0);
        __syncthreads();
        int* tmp = pin; pin = pout; pout = tmp;
    }
    int excl = 0;
    if (t < PARTW) {
        excl = pin[t] - hist[t];
        if (t < nn) rowstart[n0 + t] = base + excl;
    }
    __syncthreads();
    if (t < PARTW) hist[t] = excl;   // reuse as cursor
    __syncthreads();
    for (int i = t; i < cnt; i += 1024) {
        int2 pr = pairs[base + i];
        int pos = base + atomicAdd(&hist[pr.y - n0], 1);  // LDS atomic
        esrc[pos] = pr.x;
    }
}

// ---------------- Layer 1: x@W1 + attention coefficients ----------------

__global__ __launch_bounds__(256) void k_gemm1(const float* __restrict__ x, const float* __restrict__ W1,
        const float* __restrict__ a1s, const float* __restrict__ a1d,
        float* __restrict__ xw1, float* __restrict__ as1, float* __restrict__ ad1) {
    int n = blockIdx.x * 256 + threadIdx.x;
    if (n >= NN) return;
    float acc[F1];
#pragma unroll
    for (int c = 0; c < F1; c++) acc[c] = 0.f;
    const float4* x4 = (const float4*)(x + (size_t)n * FIN);
#pragma unroll 4
    for (int k4 = 0; k4 < FIN / 4; k4++) {
        float4 xv = x4[k4];
        float xk[4] = {xv.x, xv.y, xv.z, xv.w};
#pragma unroll
        for (int kk = 0; kk < 4; kk++) {
            int k = k4 * 4 + kk;
#pragma unroll
            for (int c = 0; c < F1; c++)
                acc[c] = fmaf(xk[kk], W1[k * F1 + c], acc[c]);  // W1 addr wave-uniform -> s_load
        }
    }
    float4* o4 = (float4*)(xw1 + (size_t)n * F1);
#pragma unroll
    for (int c4 = 0; c4 < F1 / 4; c4++)
        o4[c4] = make_float4(acc[c4*4], acc[c4*4+1], acc[c4*4+2], acc[c4*4+3]);
#pragma unroll
    for (int h = 0; h < H1; h++) {
        float ss = 0.f, dd = 0.f;
#pragma unroll
        for (int c = 0; c < C1; c++) {
            ss = fmaf(acc[h*C1+c], a1s[h*C1+c], ss);
            dd = fmaf(acc[h*C1+c], a1d[h*C1+c], dd);
        }
        as1[n*H1+h] = ss;
        ad1[n*H1+h] = dd;
    }
}

// ---------------- Layer 1: gather softmax-aggregate + bias + ELU ----------------

__global__ __launch_bounds__(256) void k_gather1(const int* __restrict__ rowstart, const int* __restrict__ esrc,
        const float* __restrict__ as1, const float* __restrict__ ad1,
        const float* __restrict__ xw1, const float* __restrict__ b1,
        float* __restrict__ h1) {
    int n = blockIdx.x * 8 + (threadIdx.x >> 5);
    if (n >= NN) return;
    int c = threadIdx.x & 31;
    int h = c >> 3;
    float adh = ad1[n * H1 + h];
    int beg = rowstart[n], end = rowstart[n + 1];
    float accn = 0.f, accd = 0.f;
    for (int i = beg; i < end; i++) {
        int s = esrc[i];
        float e = as1[s * H1 + h] + adh;
        e = (e > 0.f) ? e : NSLOPE * e;
        float ee = __expf(e);
        accd += ee;
        accn = fmaf(ee, xw1[(size_t)s * F1 + c], accn);
    }
    float y = accn / accd + b1[c];
    y = (y > 0.f) ? y : expm1f(y);   // ELU
    h1[(size_t)n * F1 + c] = y;
}

// ---------------- Layer 2: h1@W2 + attention coefficients ----------------

__global__ __launch_bounds__(256) void k_node2(const float* __restrict__ h1, const float* __restrict__ W2,
        const float* __restrict__ a2s, const float* __restrict__ a2d,
        float* __restrict__ xw2, float* __restrict__ as2, float* __restrict__ ad2) {
    int n = blockIdx.x * 256 + threadIdx.x;
    if (n >= NN) return;
    float acc[FOUT];
#pragma unroll
    for (int j = 0; j < FOUT; j++) acc[j] = 0.f;
    const float4* h4 = (const float4*)(h1 + (size_t)n * F1);
#pragma unroll
    for (int i4 = 0; i4 < F1 / 4; i4++) {
        float4 hv = h4[i4];
        float hk[4] = {hv.x, hv.y, hv.z, hv.w};
#pragma unroll
        for (int kk = 0; kk < 4; kk++) {
            int i = i4 * 4 + kk;
#pragma unroll
            for (int j = 0; j < FOUT; j++)
                acc[j] = fmaf(hk[kk], W2[i * FOUT + j], acc[j]);
        }
    }
    float ss = 0.f, dd = 0.f;
#pragma unroll
    for (int j = 0; j < FOUT; j++) {
        ss = fmaf(acc[j], a2s[j], ss);
        dd = fmaf(acc[j], a2d[j], dd);
    }
    float4* o4 = (float4*)(xw2 + (size_t)n * FOUT);
#pragma unroll
    for (int j4 = 0; j4 < FOUT / 4; j4++)
        o4[j4] = make_float4(acc[j4*4], acc[j4*4+1], acc[j4*4+2], acc[j4*4+3]);
    as2[n] = ss;
    ad2[n] = dd;
}

// ---------------- Layer 2: gather softmax-aggregate + bias + log_softmax ----------------

__global__ __launch_bounds__(256) void k_gather2(const int* __restrict__ rowstart, const int* __restrict__ esrc,
        const float* __restrict__ as2, const float* __restrict__ ad2,
        const float* __restrict__ xw2, const float* __restrict__ b2,
        float* __restrict__ out) {
    int n = blockIdx.x * 16 + (threadIdx.x >> 4);
    if (n >= NN) return;
    int c = threadIdx.x & 15;
    float adn = ad2[n];
    int beg = rowstart[n], end = rowstart[n + 1];
    float accn = 0.f, accd = 0.f;
    for (int i = beg; i < end; i++) {
        int s = esrc[i];
        float e = as2[s] + adn;
        e = (e > 0.f) ? e : NSLOPE * e;
        float ee = __expf(e);
        accd += ee;
        accn = fmaf(ee, xw2[(size_t)s * FOUT + c], accn);
    }
    float y = accn / accd + b2[c];
    float m = y;
#pragma unroll
    for (int off = 8; off > 0; off >>= 1) m = fmaxf(m, __shfl_xor(m, off));
    float ex = __expf(y - m);
    float sum = ex;
#pragma unroll
    for (int off = 8; off > 0; off >>= 1) sum += __shfl_xor(sum, off);
    out[(size_t)n * FOUT + c] = y - m - logf(sum);
}

// ---------------- launch ----------------

extern "C" void kernel_launch(void* const* d_in, const int* in_sizes, int n_in,
                              void* d_out, int out_size, void* d_ws, size_t ws_size,
                              hipStream_t stream) {
    const float* x   = (const float*)d_in[0];
    const int*   ei  = (const int*)d_in[1];
    const float* W1  = (const float*)d_in[2];
    const float* a1s = (const float*)d_in[3];
    const float* a1d = (const float*)d_in[4];
    const float* b1  = (const float*)d_in[5];
    const float* W2  = (const float*)d_in[6];
    const float* a2s = (const float*)d_in[7];
    const float* a2d = (const float*)d_in[8];
    const float* b2  = (const float*)d_in[9];
    float* out = (float*)d_out;

    const int* srcA = ei;        // edge_index[0]
    const int* dstA = ei + NE;   // edge_index[1]

    char* w = (char*)d_ws;
    size_t off = 0;
    auto carve = [&](size_t bytes) -> void* {
        void* p = w + off;
        off = (off + bytes + 255) & ~(size_t)255;
        return p;
    };
    float* xw1     = (float*)carve((size_t)NN * F1 * 4);     // 12.8 MB
    float* as1     = (float*)carve((size_t)NN * H1 * 4);
    float* ad1     = (float*)carve((size_t)NN * H1 * 4);
    // h1..ad2 form a ~20MB block; `pairs` (13.6MB) aliases it — pairs is dead
    // before gather1 writes h1 (stream-ordered), so this is safe.
    size_t h1_off  = off;
    float* h1      = (float*)carve((size_t)NN * F1 * 4);     // 12.8 MB
    float* xw2     = (float*)carve((size_t)NN * FOUT * 4);   // 6.4 MB
    float* as2     = (float*)carve((size_t)NN * 4);
    float* ad2     = (float*)carve((size_t)NN * 4);
    int2*  pairs   = (int2*)(w + h1_off);                    // alias
    int* rowstart  = (int*)carve((size_t)(NN + 1) * 4);
    int* esrc      = (int*)carve((size_t)ET * 4);            // 6.8 MB
    int* bh        = (int*)carve((size_t)MTOT * 4);          // 163 KB
    (void)ws_size; (void)in_sizes; (void)n_in; (void)out_size;

    k_hist  <<<NBLK, 256, 0, stream>>>(dstA, bh);
    k_pscan <<<1, 1024, 0, stream>>>(bh, rowstart);
    k_part  <<<NBLK, 256, 0, stream>>>(srcA, dstA, bh, pairs);
    k_sort  <<<NPART, 1024, 0, stream>>>(bh, pairs, rowstart, esrc);

    k_gemm1  <<<(NN + 255) / 256, 256, 0, stream>>>(x, W1, a1s, a1d, xw1, as1, ad1);
    k_gather1<<<(NN + 7) / 8, 256, 0, stream>>>(rowstart, esrc, as1, ad1, xw1, b1, h1);
    k_node2  <<<(NN + 255) / 256, 256, 0, stream>>>(h1, W2, a2s, a2d, xw2, as2, ad2);
    k_gather2<<<(NN + 15) / 16, 256, 0, stream>>>(rowstart, esrc, as2, ad2, xw2, b2, out);
}

// Round 4
// 324.023 us; speedup vs baseline: 8.4362x; 1.1305x over previous
//
#include <hip/hip_runtime.h>
#include <math.h>

// Problem constants (from setup_inputs)
#define NN 100000            // nodes
#define NE 1600000           // real edges
#define ET (NE + NN)         // edges + self loops = 1,700,000
#define FIN 128
#define H1 4
#define C1 8
#define F1 32                // H1*C1
#define FOUT 16
#define NSLOPE 0.2f

// Radix-partition parameters (CSR build, zero global atomics)
#define PARTW 512                          // nodes per dst-partition
#define NPART ((NN + PARTW - 1) / PARTW)   // 196
#define CHUNK 8192                         // edges per hist/part block
#define NBLK ((ET + CHUNK - 1) / CHUNK)    // 208
#define MTOT (NPART * NBLK)                // 40768 scan entries

typedef _Float16 half8 __attribute__((ext_vector_type(8)));

// ---------------- wave/block scan helpers ----------------

__device__ inline int wave_incl_scan(int v) {
#pragma unroll
    for (int off = 1; off < 64; off <<= 1) {
        int u = __shfl_up(v, off);
        if ((threadIdx.x & 63) >= off) v += u;
    }
    return v;
}

// ---------------- CSR build: 3-pass radix partition + per-partition sort ----------------

// Pass 1: per-block LDS histogram over 196 dst-partitions.
__global__ __launch_bounds__(1024) void k_hist(const int* __restrict__ dstA, int* __restrict__ bh) {
    __shared__ int h[NPART];
    int t = threadIdx.x;
    for (int i = t; i < NPART; i += 1024) h[i] = 0;
    __syncthreads();
    int base = blockIdx.x * CHUNK;
#pragma unroll
    for (int k = 0; k < CHUNK / 1024; k++) {
        int e = base + k * 1024 + t;
        if (e < ET) {
            int d = (e < NE) ? dstA[e] : (e - NE);   // virtual self-loop edges
            atomicAdd(&h[d >> 9], 1);
        }
    }
    __syncthreads();
    for (int i = t; i < NPART; i += 1024) bh[i * NBLK + blockIdx.x] = h[i];  // column-major
}

// Pass 2: single-block exclusive scan of bh[MTOT] (in place).
__global__ __launch_bounds__(1024) void k_pscan(int* __restrict__ bh, int* __restrict__ rowstart) {
    __shared__ int wsum[16];
    int t = threadIdx.x;
    int wid = t >> 6, lane = t & 63;
    int carry = 0;
    for (int it = 0; it < (MTOT + 1023) / 1024; it++) {
        int idx = it * 1024 + t;
        int v = (idx < MTOT) ? bh[idx] : 0;
        int incl = wave_incl_scan(v);
        if (lane == 63) wsum[wid] = incl;
        __syncthreads();
        if (wid == 0) {
            int wv = (lane < 16) ? wsum[lane] : 0;
            wv = wave_incl_scan(wv);
            if (lane < 16) wsum[lane] = wv;
        }
        __syncthreads();
        int blockincl = incl + (wid ? wsum[wid - 1] : 0);
        int total = wsum[15];
        if (idx < MTOT) bh[idx] = carry + blockincl - v;  // exclusive
        carry += total;
        __syncthreads();
    }
    if (t == 0) rowstart[NN] = ET;
}

// Pass 3: scatter packed (dloc<<17)|src into partition-ordered buffer.
// LDS cursors seeded from the scan -> pre-reserved slots; NO global atomics.
__global__ __launch_bounds__(1024) void k_part(const int* __restrict__ srcA, const int* __restrict__ dstA,
                                               const int* __restrict__ bh, int* __restrict__ pairs) {
    __shared__ int cur[NPART];
    int t = threadIdx.x;
    for (int i = t; i < NPART; i += 1024) cur[i] = bh[i * NBLK + blockIdx.x];
    __syncthreads();
    int base = blockIdx.x * CHUNK;
#pragma unroll
    for (int k = 0; k < CHUNK / 1024; k++) {
        int e = base + k * 1024 + t;
        if (e < ET) {
            int s, d;
            if (e < NE) { s = srcA[e]; d = dstA[e]; }
            else        { s = e - NE;  d = s; }
            int pos = atomicAdd(&cur[d >> 9], 1);   // LDS atomic
            pairs[pos] = ((d & 511) << 17) | s;     // src < 2^17, dloc < 2^9
        }
    }
}

// Pass 4: one block per partition: LDS counting sort of <=512 local nodes.
// Emits rowstart and esrc.
__global__ __launch_bounds__(1024) void k_sort(const int* __restrict__ bh, const int* __restrict__ pairs,
                                               int* __restrict__ rowstart, int* __restrict__ esrc) {
    __shared__ int hist[PARTW];
    __shared__ int sa[PARTW], sb[PARTW];
    int p = blockIdx.x;
    int t = threadIdx.x;
    int n0 = p << 9;
    int nn = min(PARTW, NN - n0);
    int base = bh[p * NBLK];
    int endp = (p == NPART - 1) ? ET : bh[(p + 1) * NBLK];
    int cnt = endp - base;
    if (t < PARTW) hist[t] = 0;
    __syncthreads();
    for (int i = t; i < cnt; i += 1024)
        atomicAdd(&hist[pairs[base + i] >> 17], 1);
    __syncthreads();
    if (t < PARTW) sa[t] = hist[t];
    __syncthreads();
    int* pin = sa; int* pout = sb;
    for (int off = 1; off < PARTW; off <<= 1) {
        if (t < PARTW) pout[t] = pin[t] + ((t >= off) ? pin[t - off] : 0);
        __syncthreads();
        int* tmp = pin; pin = pout; pout = tmp;
    }
    int excl = 0;
    if (t < PARTW) {
        excl = pin[t] - hist[t];
        if (t < nn) rowstart[n0 + t] = base + excl;
    }
    __syncthreads();
    if (t < PARTW) hist[t] = excl;   // reuse as cursor
    __syncthreads();
    for (int i = t; i < cnt; i += 1024) {
        int v = pairs[base + i];
        int pos = base + atomicAdd(&hist[v >> 17], 1);  // LDS atomic
        esrc[pos] = v & 0x1FFFF;
    }
}

// ---------------- Layer 1: x@W1 + attention coefficients (xw1 stored fp16) ----------------

__global__ __launch_bounds__(256) void k_gemm1(const float* __restrict__ x, const float* __restrict__ W1,
        const float* __restrict__ a1s, const float* __restrict__ a1d,
        _Float16* __restrict__ xw1h, float* __restrict__ as1, float* __restrict__ ad1) {
    int n = blockIdx.x * 256 + threadIdx.x;
    if (n >= NN) return;
    float acc[F1];
#pragma unroll
    for (int c = 0; c < F1; c++) acc[c] = 0.f;
    const float4* x4 = (const float4*)(x + (size_t)n * FIN);
#pragma unroll 4
    for (int k4 = 0; k4 < FIN / 4; k4++) {
        float4 xv = x4[k4];
        float xk[4] = {xv.x, xv.y, xv.z, xv.w};
#pragma unroll
        for (int kk = 0; kk < 4; kk++) {
            int k = k4 * 4 + kk;
#pragma unroll
            for (int c = 0; c < F1; c++)
                acc[c] = fmaf(xk[kk], W1[k * F1 + c], acc[c]);  // W1 addr wave-uniform -> s_load
        }
    }
    half8* o8 = (half8*)(xw1h + (size_t)n * F1);
#pragma unroll
    for (int c8 = 0; c8 < F1 / 8; c8++) {
        half8 o;
#pragma unroll
        for (int k = 0; k < 8; k++) o[k] = (_Float16)acc[c8 * 8 + k];
        o8[c8] = o;
    }
#pragma unroll
    for (int h = 0; h < H1; h++) {
        float ss = 0.f, dd = 0.f;
#pragma unroll
        for (int c = 0; c < C1; c++) {
            ss = fmaf(acc[h*C1+c], a1s[h*C1+c], ss);
            dd = fmaf(acc[h*C1+c], a1d[h*C1+c], dd);
        }
        as1[n*H1+h] = ss;
        ad1[n*H1+h] = dd;
    }
}

// ---------------- Layer 1 gather + ELU + fused layer-2 linear ----------------
// 64 lanes per node: halves process interleaved edges (unroll x2 -> 4 edges in
// flight). Epilogue: h1 row lives in lanes 0..31; 32x16 matmul via __shfl
// broadcasts against preloaded W2 column -> xw2 (fp16) + as2/ad2 directly.

__global__ __launch_bounds__(256) void k_gather1(const int* __restrict__ rowstart, const int* __restrict__ esrc,
        const float* __restrict__ as1, const float* __restrict__ ad1,
        const _Float16* __restrict__ xw1h, const float* __restrict__ b1,
        const float* __restrict__ W2, const float* __restrict__ a2s, const float* __restrict__ a2d,
        _Float16* __restrict__ xw2h, float* __restrict__ as2, float* __restrict__ ad2) {
    int n = blockIdx.x * 4 + (threadIdx.x >> 6);
    if (n >= NN) return;
    int l = threadIdx.x & 63;
    int c = l & 31;
    int h = c >> 3;
    int half = l >> 5;
    int j = l & 15;
    float w2col[F1];
#pragma unroll
    for (int i = 0; i < F1; i++) w2col[i] = W2[i * FOUT + j];
    float adh = ad1[n * H1 + h];
    int beg = rowstart[n], end = rowstart[n + 1];
    float accn = 0.f, accd = 0.f;
    int i = beg + half;
    for (; i + 2 < end; i += 4) {
        int s0 = esrc[i], s1 = esrc[i + 2];
        float e0 = as1[s0 * H1 + h] + adh;
        float e1 = as1[s1 * H1 + h] + adh;
        float x0 = (float)xw1h[s0 * F1 + c];
        float x1 = (float)xw1h[s1 * F1 + c];
        e0 = (e0 > 0.f) ? e0 : NSLOPE * e0;
        e1 = (e1 > 0.f) ? e1 : NSLOPE * e1;
        float ee0 = __expf(e0), ee1 = __expf(e1);
        accd += ee0 + ee1;
        accn = fmaf(ee0, x0, fmaf(ee1, x1, accn));
    }
    if (i < end) {
        int s0 = esrc[i];
        float e0 = as1[s0 * H1 + h] + adh;
        float x0 = (float)xw1h[s0 * F1 + c];
        e0 = (e0 > 0.f) ? e0 : NSLOPE * e0;
        float ee0 = __expf(e0);
        accd += ee0;
        accn = fmaf(ee0, x0, accn);
    }
    accn += __shfl_xor(accn, 32);
    accd += __shfl_xor(accd, 32);
    float y = accn / accd + b1[c];
    y = (y > 0.f) ? y : expm1f(y);   // ELU -> h1 value for channel c
    // fused node2: xw2[n][j] = sum_i h1[i] * W2[i][j]
    float acc2 = 0.f;
#pragma unroll
    for (int i2 = 0; i2 < F1; i2++)
        acc2 = fmaf(__shfl(y, i2), w2col[i2], acc2);
    float ss = acc2 * a2s[j];
    float dd = acc2 * a2d[j];
#pragma unroll
    for (int off = 8; off > 0; off >>= 1) {
        ss += __shfl_xor(ss, off);
        dd += __shfl_xor(dd, off);
    }
    if (l < 16) xw2h[(size_t)n * FOUT + j] = (_Float16)acc2;
    if (l == 0) { as2[n] = ss; ad2[n] = dd; }
}

// ---------------- Layer 2: gather softmax-aggregate + bias + log_softmax ----------------
// 64 lanes per node: quarters process interleaved edges (unroll x2 -> 8 in flight).

__global__ __launch_bounds__(256) void k_gather2(const int* __restrict__ rowstart, const int* __restrict__ esrc,
        const float* __restrict__ as2, const float* __restrict__ ad2,
        const _Float16* __restrict__ xw2h, const float* __restrict__ b2,
        float* __restrict__ out) {
    int n = blockIdx.x * 4 + (threadIdx.x >> 6);
    if (n >= NN) return;
    int l = threadIdx.x & 63;
    int c = l & 15;
    int q = l >> 4;
    float adn = ad2[n];
    int beg = rowstart[n], end = rowstart[n + 1];
    float accn = 0.f, accd = 0.f;
    int i = beg + q;
    for (; i + 4 < end; i += 8) {
        int s0 = esrc[i], s1 = esrc[i + 4];
        float e0 = as2[s0] + adn;
        float e1 = as2[s1] + adn;
        float x0 = (float)xw2h[s0 * FOUT + c];
        float x1 = (float)xw2h[s1 * FOUT + c];
        e0 = (e0 > 0.f) ? e0 : NSLOPE * e0;
        e1 = (e1 > 0.f) ? e1 : NSLOPE * e1;
        float ee0 = __expf(e0), ee1 = __expf(e1);
        accd += ee0 + ee1;
        accn = fmaf(ee0, x0, fmaf(ee1, x1, accn));
    }
    if (i < end) {
        int s0 = esrc[i];
        float e0 = as2[s0] + adn;
        float x0 = (float)xw2h[s0 * FOUT + c];
        e0 = (e0 > 0.f) ? e0 : NSLOPE * e0;
        float ee0 = __expf(e0);
        accd += ee0;
        accn = fmaf(ee0, x0, accn);
    }
    accn += __shfl_xor(accn, 16);
    accn += __shfl_xor(accn, 32);
    accd += __shfl_xor(accd, 16);
    accd += __shfl_xor(accd, 32);
    float y = accn / accd + b2[c];
    float m = y;
#pragma unroll
    for (int off = 8; off > 0; off >>= 1) m = fmaxf(m, __shfl_xor(m, off));
    float ex = __expf(y - m);
    float sum = ex;
#pragma unroll
    for (int off = 8; off > 0; off >>= 1) sum += __shfl_xor(sum, off);
    if (l < 16) out[(size_t)n * FOUT + c] = y - m - logf(sum);
}

// ---------------- launch ----------------

extern "C" void kernel_launch(void* const* d_in, const int* in_sizes, int n_in,
                              void* d_out, int out_size, void* d_ws, size_t ws_size,
                              hipStream_t stream) {
    const float* x   = (const float*)d_in[0];
    const int*   ei  = (const int*)d_in[1];
    const float* W1  = (const float*)d_in[2];
    const float* a1s = (const float*)d_in[3];
    const float* a1d = (const float*)d_in[4];
    const float* b1  = (const float*)d_in[5];
    const float* W2  = (const float*)d_in[6];
    const float* a2s = (const float*)d_in[7];
    const float* a2d = (const float*)d_in[8];
    const float* b2  = (const float*)d_in[9];
    float* out = (float*)d_out;

    const int* srcA = ei;        // edge_index[0]
    const int* dstA = ei + NE;   // edge_index[1]

    char* w = (char*)d_ws;
    size_t off = 0;
    auto carve = [&](size_t bytes) -> void* {
        void* p = w + off;
        off = (off + bytes + 255) & ~(size_t)255;
        return p;
    };
    _Float16* xw1h = (_Float16*)carve((size_t)NN * F1 * 2);   // 6.4 MB
    float* as1     = (float*)carve((size_t)NN * H1 * 4);      // 1.6 MB
    float* ad1     = (float*)carve((size_t)NN * H1 * 4);      // 1.6 MB
    _Float16* xw2h = (_Float16*)carve((size_t)NN * FOUT * 2); // 3.2 MB
    float* as2     = (float*)carve((size_t)NN * 4);
    float* ad2     = (float*)carve((size_t)NN * 4);
    int* rowstart  = (int*)carve((size_t)(NN + 1) * 4);
    int* esrc      = (int*)carve((size_t)ET * 4);             // 6.8 MB
    int* pairs     = (int*)carve((size_t)ET * 4);             // 6.8 MB
    int* bh        = (int*)carve((size_t)MTOT * 4);           // 163 KB
    (void)ws_size; (void)in_sizes; (void)n_in; (void)out_size;

    k_hist  <<<NBLK, 1024, 0, stream>>>(dstA, bh);
    k_pscan <<<1, 1024, 0, stream>>>(bh, rowstart);
    k_part  <<<NBLK, 1024, 0, stream>>>(srcA, dstA, bh, pairs);
    k_sort  <<<NPART, 1024, 0, stream>>>(bh, pairs, rowstart, esrc);

    k_gemm1  <<<(NN + 255) / 256, 256, 0, stream>>>(x, W1, a1s, a1d, xw1h, as1, ad1);
    k_gather1<<<(NN + 3) / 4, 256, 0, stream>>>(rowstart, esrc, as1, ad1, xw1h, b1,
                                                W2, a2s, a2d, xw2h, as2, ad2);
    k_gather2<<<(NN + 3) / 4, 256, 0, stream>>>(rowstart, esrc, as2, ad2, xw2h, b2, out);
}

// Round 5
// 316.384 us; speedup vs baseline: 8.6399x; 1.0241x over previous
//
#include <hip/hip_runtime.h>
#include <math.h>

// Problem constants (from setup_inputs)
#define NN 100000            // nodes
#define NE 1600000           // real edges
#define ET (NE + NN)         // edges + self loops = 1,700,000
#define FIN 128
#define H1 4
#define C1 8
#define F1 32                // H1*C1
#define FOUT 16
#define NSLOPE 0.2f

// Radix-partition parameters (CSR build, zero global atomics)
#define PARTW 512                          // nodes per dst-partition
#define NPART ((NN + PARTW - 1) / PARTW)   // 196
#define CHUNK 8192                         // edges per hist/part block
#define NBLK ((ET + CHUNK - 1) / CHUNK)    // 208
#define MTOT (NPART * NBLK)                // 40768 scan entries

typedef _Float16 half8 __attribute__((ext_vector_type(8)));

// ---------------- wave/block scan helpers ----------------

__device__ inline int wave_incl_scan(int v) {
#pragma unroll
    for (int off = 1; off < 64; off <<= 1) {
        int u = __shfl_up(v, off);
        if ((threadIdx.x & 63) >= off) v += u;
    }
    return v;
}

// ---------------- CSR build: 3-pass radix partition + per-partition sort ----------------

// Pass 1: per-block LDS histogram over 196 dst-partitions.
__global__ __launch_bounds__(1024) void k_hist(const int* __restrict__ dstA, int* __restrict__ bh) {
    __shared__ int h[NPART];
    int t = threadIdx.x;
    for (int i = t; i < NPART; i += 1024) h[i] = 0;
    __syncthreads();
    int base = blockIdx.x * CHUNK;
#pragma unroll
    for (int k = 0; k < CHUNK / 1024; k++) {
        int e = base + k * 1024 + t;
        if (e < ET) {
            int d = (e < NE) ? dstA[e] : (e - NE);   // virtual self-loop edges
            atomicAdd(&h[d >> 9], 1);
        }
    }
    __syncthreads();
    for (int i = t; i < NPART; i += 1024) bh[i * NBLK + blockIdx.x] = h[i];  // column-major
}

// Pass 2: single-block exclusive scan of bh[MTOT] (in place).
__global__ __launch_bounds__(1024) void k_pscan(int* __restrict__ bh, int* __restrict__ rowstart) {
    __shared__ int wsum[16];
    int t = threadIdx.x;
    int wid = t >> 6, lane = t & 63;
    int carry = 0;
    for (int it = 0; it < (MTOT + 1023) / 1024; it++) {
        int idx = it * 1024 + t;
        int v = (idx < MTOT) ? bh[idx] : 0;
        int incl = wave_incl_scan(v);
        if (lane == 63) wsum[wid] = incl;
        __syncthreads();
        if (wid == 0) {
            int wv = (lane < 16) ? wsum[lane] : 0;
            wv = wave_incl_scan(wv);
            if (lane < 16) wsum[lane] = wv;
        }
        __syncthreads();
        int blockincl = incl + (wid ? wsum[wid - 1] : 0);
        int total = wsum[15];
        if (idx < MTOT) bh[idx] = carry + blockincl - v;  // exclusive
        carry += total;
        __syncthreads();
    }
    if (t == 0) rowstart[NN] = ET;
}

// Pass 3: scatter packed (dloc<<17)|src into partition-ordered buffer.
// LDS cursors seeded from the scan -> pre-reserved slots; NO global atomics.
__global__ __launch_bounds__(1024) void k_part(const int* __restrict__ srcA, const int* __restrict__ dstA,
                                               const int* __restrict__ bh, int* __restrict__ pairs) {
    __shared__ int cur[NPART];
    int t = threadIdx.x;
    for (int i = t; i < NPART; i += 1024) cur[i] = bh[i * NBLK + blockIdx.x];
    __syncthreads();
    int base = blockIdx.x * CHUNK;
#pragma unroll
    for (int k = 0; k < CHUNK / 1024; k++) {
        int e = base + k * 1024 + t;
        if (e < ET) {
            int s, d;
            if (e < NE) { s = srcA[e]; d = dstA[e]; }
            else        { s = e - NE;  d = s; }
            int pos = atomicAdd(&cur[d >> 9], 1);   // LDS atomic
            pairs[pos] = ((d & 511) << 17) | s;     // src < 2^17, dloc < 2^9
        }
    }
}

// Pass 4: one block per partition: LDS counting sort of <=512 local nodes.
__global__ __launch_bounds__(1024) void k_sort(const int* __restrict__ bh, const int* __restrict__ pairs,
                                               int* __restrict__ rowstart, int* __restrict__ esrc) {
    __shared__ int hist[PARTW];
    __shared__ int sa[PARTW], sb[PARTW];
    int p = blockIdx.x;
    int t = threadIdx.x;
    int n0 = p << 9;
    int nn = min(PARTW, NN - n0);
    int base = bh[p * NBLK];
    int endp = (p == NPART - 1) ? ET : bh[(p + 1) * NBLK];
    int cnt = endp - base;
    if (t < PARTW) hist[t] = 0;
    __syncthreads();
    for (int i = t; i < cnt; i += 1024)
        atomicAdd(&hist[pairs[base + i] >> 17], 1);
    __syncthreads();
    if (t < PARTW) sa[t] = hist[t];
    __syncthreads();
    int* pin = sa; int* pout = sb;
    for (int off = 1; off < PARTW; off <<= 1) {
        if (t < PARTW) pout[t] = pin[t] + ((t >= off) ? pin[t - off] : 0);
        __syncthreads();
        int* tmp = pin; pin = pout; pout = tmp;
    }
    int excl = 0;
    if (t < PARTW) {
        excl = pin[t] - hist[t];
        if (t < nn) rowstart[n0 + t] = base + excl;
    }
    __syncthreads();
    if (t < PARTW) hist[t] = excl;   // reuse as cursor
    __syncthreads();
    for (int i = t; i < cnt; i += 1024) {
        int v = pairs[base + i];
        int pos = base + atomicAdd(&hist[v >> 17], 1);  // LDS atomic
        esrc[pos] = v & 0x1FFFF;
    }
}

// ---------------- Layer 1: x@W1 + attention coefficients (xw1 stored fp16) ----------------

__global__ __launch_bounds__(256) void k_gemm1(const float* __restrict__ x, const float* __restrict__ W1,
        const float* __restrict__ a1s, const float* __restrict__ a1d,
        _Float16* __restrict__ xw1h, float* __restrict__ as1, float* __restrict__ ad1) {
    int n = blockIdx.x * 256 + threadIdx.x;
    if (n >= NN) return;
    float acc[F1];
#pragma unroll
    for (int c = 0; c < F1; c++) acc[c] = 0.f;
    const float4* x4 = (const float4*)(x + (size_t)n * FIN);
#pragma unroll 4
    for (int k4 = 0; k4 < FIN / 4; k4++) {
        float4 xv = x4[k4];
        float xk[4] = {xv.x, xv.y, xv.z, xv.w};
#pragma unroll
        for (int kk = 0; kk < 4; kk++) {
            int k = k4 * 4 + kk;
#pragma unroll
            for (int c = 0; c < F1; c++)
                acc[c] = fmaf(xk[kk], W1[k * F1 + c], acc[c]);  // W1 addr wave-uniform -> s_load
        }
    }
    half8* o8 = (half8*)(xw1h + (size_t)n * F1);
#pragma unroll
    for (int c8 = 0; c8 < F1 / 8; c8++) {
        half8 o;
#pragma unroll
        for (int k = 0; k < 8; k++) o[k] = (_Float16)acc[c8 * 8 + k];
        o8[c8] = o;
    }
#pragma unroll
    for (int h = 0; h < H1; h++) {
        float ss = 0.f, dd = 0.f;
#pragma unroll
        for (int c = 0; c < C1; c++) {
            ss = fmaf(acc[h*C1+c], a1s[h*C1+c], ss);
            dd = fmaf(acc[h*C1+c], a1d[h*C1+c], dd);
        }
        as1[n*H1+h] = ss;
        ad1[n*H1+h] = dd;
    }
}

// ---------------- Layer 1 gather: softmax-aggregate + bias + ELU -> h1 (fp16) ----------------
// 64 lanes per node (1 wave/node). Halves process interleaved edges, unroll x4
// -> 8 independent gathers in flight per wave. Lean epilogue (node2 unfused).

__global__ __launch_bounds__(256) void k_gather1(const int* __restrict__ rowstart, const int* __restrict__ esrc,
        const float* __restrict__ as1, const float* __restrict__ ad1,
        const _Float16* __restrict__ xw1h, const float* __restrict__ b1,
        _Float16* __restrict__ h1h) {
    int n = blockIdx.x * 4 + (threadIdx.x >> 6);
    if (n >= NN) return;
    int l = threadIdx.x & 63;
    int c = l & 31;
    int h = c >> 3;
    int half = l >> 5;
    float adh = ad1[n * H1 + h];
    int beg = rowstart[n], end = rowstart[n + 1];
    float accn = 0.f, accd = 0.f;
    int i = beg + half;
    for (; i + 6 < end; i += 8) {
        int s0 = esrc[i], s1 = esrc[i + 2], s2 = esrc[i + 4], s3 = esrc[i + 6];
        float e0 = as1[s0 * H1 + h] + adh;
        float e1 = as1[s1 * H1 + h] + adh;
        float e2 = as1[s2 * H1 + h] + adh;
        float e3 = as1[s3 * H1 + h] + adh;
        float x0 = (float)xw1h[s0 * F1 + c];
        float x1 = (float)xw1h[s1 * F1 + c];
        float x2 = (float)xw1h[s2 * F1 + c];
        float x3 = (float)xw1h[s3 * F1 + c];
        e0 = (e0 > 0.f) ? e0 : NSLOPE * e0;
        e1 = (e1 > 0.f) ? e1 : NSLOPE * e1;
        e2 = (e2 > 0.f) ? e2 : NSLOPE * e2;
        e3 = (e3 > 0.f) ? e3 : NSLOPE * e3;
        float ee0 = __expf(e0), ee1 = __expf(e1), ee2 = __expf(e2), ee3 = __expf(e3);
        accd += (ee0 + ee1) + (ee2 + ee3);
        accn = fmaf(ee0, x0, fmaf(ee1, x1, fmaf(ee2, x2, fmaf(ee3, x3, accn))));
    }
    for (; i < end; i += 2) {
        int s0 = esrc[i];
        float e0 = as1[s0 * H1 + h] + adh;
        float x0 = (float)xw1h[s0 * F1 + c];
        e0 = (e0 > 0.f) ? e0 : NSLOPE * e0;
        float ee0 = __expf(e0);
        accd += ee0;
        accn = fmaf(ee0, x0, accn);
    }
    accn += __shfl_xor(accn, 32);
    accd += __shfl_xor(accd, 32);
    float y = accn / accd + b1[c];
    y = (y > 0.f) ? y : expm1f(y);   // ELU
    if (l < 32) h1h[(size_t)n * F1 + c] = (_Float16)y;
}

// ---------------- Layer 2 node transform: h1@W2 + attention coefficients ----------------
// 1 thread per node: 512 register FMAs, reads 64B fp16 row, writes 32B fp16 row.

__global__ __launch_bounds__(256) void k_node2(const _Float16* __restrict__ h1h, const float* __restrict__ W2,
        const float* __restrict__ a2s, const float* __restrict__ a2d,
        _Float16* __restrict__ xw2h, float* __restrict__ as2, float* __restrict__ ad2) {
    int n = blockIdx.x * 256 + threadIdx.x;
    if (n >= NN) return;
    float acc[FOUT];
#pragma unroll
    for (int j = 0; j < FOUT; j++) acc[j] = 0.f;
    const half8* h8 = (const half8*)(h1h + (size_t)n * F1);
#pragma unroll
    for (int i8 = 0; i8 < F1 / 8; i8++) {
        half8 hv = h8[i8];
#pragma unroll
        for (int kk = 0; kk < 8; kk++) {
            float hk = (float)hv[kk];
            int i = i8 * 8 + kk;
#pragma unroll
            for (int j = 0; j < FOUT; j++)
                acc[j] = fmaf(hk, W2[i * FOUT + j], acc[j]);   // wave-uniform -> scalar
        }
    }
    float ss = 0.f, dd = 0.f;
#pragma unroll
    for (int j = 0; j < FOUT; j++) {
        ss = fmaf(acc[j], a2s[j], ss);
        dd = fmaf(acc[j], a2d[j], dd);
    }
    half8* o8 = (half8*)(xw2h + (size_t)n * FOUT);
#pragma unroll
    for (int j8 = 0; j8 < FOUT / 8; j8++) {
        half8 o;
#pragma unroll
        for (int k = 0; k < 8; k++) o[k] = (_Float16)acc[j8 * 8 + k];
        o8[j8] = o;
    }
    as2[n] = ss;
    ad2[n] = dd;
}

// ---------------- Layer 2: gather softmax-aggregate + bias + log_softmax ----------------
// 64 lanes per node: quarters process interleaved edges (unroll x2 -> 8 in flight).

__global__ __launch_bounds__(256) void k_gather2(const int* __restrict__ rowstart, const int* __restrict__ esrc,
        const float* __restrict__ as2, const float* __restrict__ ad2,
        const _Float16* __restrict__ xw2h, const float* __restrict__ b2,
        float* __restrict__ out) {
    int n = blockIdx.x * 4 + (threadIdx.x >> 6);
    if (n >= NN) return;
    int l = threadIdx.x & 63;
    int c = l & 15;
    int q = l >> 4;
    float adn = ad2[n];
    int beg = rowstart[n], end = rowstart[n + 1];
    float accn = 0.f, accd = 0.f;
    int i = beg + q;
    for (; i + 4 < end; i += 8) {
        int s0 = esrc[i], s1 = esrc[i + 4];
        float e0 = as2[s0] + adn;
        float e1 = as2[s1] + adn;
        float x0 = (float)xw2h[s0 * FOUT + c];
        float x1 = (float)xw2h[s1 * FOUT + c];
        e0 = (e0 > 0.f) ? e0 : NSLOPE * e0;
        e1 = (e1 > 0.f) ? e1 : NSLOPE * e1;
        float ee0 = __expf(e0), ee1 = __expf(e1);
        accd += ee0 + ee1;
        accn = fmaf(ee0, x0, fmaf(ee1, x1, accn));
    }
    if (i < end) {
        int s0 = esrc[i];
        float e0 = as2[s0] + adn;
        float x0 = (float)xw2h[s0 * FOUT + c];
        e0 = (e0 > 0.f) ? e0 : NSLOPE * e0;
        float ee0 = __expf(e0);
        accd += ee0;
        accn = fmaf(ee0, x0, accn);
    }
    accn += __shfl_xor(accn, 16);
    accn += __shfl_xor(accn, 32);
    accd += __shfl_xor(accd, 16);
    accd += __shfl_xor(accd, 32);
    float y = accn / accd + b2[c];
    float m = y;
#pragma unroll
    for (int off = 8; off > 0; off >>= 1) m = fmaxf(m, __shfl_xor(m, off));
    float ex = __expf(y - m);
    float sum = ex;
#pragma unroll
    for (int off = 8; off > 0; off >>= 1) sum += __shfl_xor(sum, off);
    if (l < 16) out[(size_t)n * FOUT + c] = y - m - logf(sum);
}

// ---------------- launch ----------------

extern "C" void kernel_launch(void* const* d_in, const int* in_sizes, int n_in,
                              void* d_out, int out_size, void* d_ws, size_t ws_size,
                              hipStream_t stream) {
    const float* x   = (const float*)d_in[0];
    const int*   ei  = (const int*)d_in[1];
    const float* W1  = (const float*)d_in[2];
    const float* a1s = (const float*)d_in[3];
    const float* a1d = (const float*)d_in[4];
    const float* b1  = (const float*)d_in[5];
    const float* W2  = (const float*)d_in[6];
    const float* a2s = (const float*)d_in[7];
    const float* a2d = (const float*)d_in[8];
    const float* b2  = (const float*)d_in[9];
    float* out = (float*)d_out;

    const int* srcA = ei;        // edge_index[0]
    const int* dstA = ei + NE;   // edge_index[1]

    char* w = (char*)d_ws;
    size_t off = 0;
    auto carve = [&](size_t bytes) -> void* {
        void* p = w + off;
        off = (off + bytes + 255) & ~(size_t)255;
        return p;
    };
    _Float16* xw1h = (_Float16*)carve((size_t)NN * F1 * 2);   // 6.4 MB
    float* as1     = (float*)carve((size_t)NN * H1 * 4);      // 1.6 MB
    float* ad1     = (float*)carve((size_t)NN * H1 * 4);      // 1.6 MB
    _Float16* h1h  = (_Float16*)carve((size_t)NN * F1 * 2);   // 6.4 MB
    _Float16* xw2h = (_Float16*)carve((size_t)NN * FOUT * 2); // 3.2 MB
    float* as2     = (float*)carve((size_t)NN * 4);
    float* ad2     = (float*)carve((size_t)NN * 4);
    int* rowstart  = (int*)carve((size_t)(NN + 1) * 4);
    int* esrc      = (int*)carve((size_t)ET * 4);             // 6.8 MB
    int* pairs     = (int*)carve((size_t)ET * 4);             // 6.8 MB
    int* bh        = (int*)carve((size_t)MTOT * 4);           // 163 KB
    (void)ws_size; (void)in_sizes; (void)n_in; (void)out_size;

    k_hist  <<<NBLK, 1024, 0, stream>>>(dstA, bh);
    k_pscan <<<1, 1024, 0, stream>>>(bh, rowstart);
    k_part  <<<NBLK, 1024, 0, stream>>>(srcA, dstA, bh, pairs);
    k_sort  <<<NPART, 1024, 0, stream>>>(bh, pairs, rowstart, esrc);

    k_gemm1  <<<(NN + 255) / 256, 256, 0, stream>>>(x, W1, a1s, a1d, xw1h, as1, ad1);
    k_gather1<<<(NN + 3) / 4, 256, 0, stream>>>(rowstart, esrc, as1, ad1, xw1h, b1, h1h);
    k_node2  <<<(NN + 255) / 256, 256, 0, stream>>>(h1h, W2, a2s, a2d, xw2h, as2, ad2);
    k_gather2<<<(NN + 3) / 4, 256, 0, stream>>>(rowstart, esrc, as2, ad2, xw2h, b2, out);
}

// Round 6
// 279.149 us; speedup vs baseline: 9.7924x; 1.1334x over previous
//
#include <hip/hip_runtime.h>
#include <math.h>

// Problem constants (from setup_inputs)
#define NN 100000            // nodes
#define NE 1600000           // real edges
#define ET (NE + NN)         // edges + self loops = 1,700,000
#define FIN 128
#define H1 4
#define C1 8
#define F1 32                // H1*C1
#define FOUT 16
#define NSLOPE 0.2f

// Radix-partition parameters (CSR build, zero global atomics)
#define PARTW 256                          // nodes per dst-partition
#define PSHIFT 8
#define NPART ((NN + PARTW - 1) / PARTW)   // 391
#define CHUNK 8192                         // edges per hist/part block
#define NBLK ((ET + CHUNK - 1) / CHUNK)    // 208
#define MTOT (NPART * NBLK)                // 81328

typedef _Float16 half8 __attribute__((ext_vector_type(8)));

// ---------------- scan helpers ----------------

__device__ inline int wave_incl_scan(int v) {
#pragma unroll
    for (int off = 1; off < 64; off <<= 1) {
        int u = __shfl_up(v, off);
        if ((threadIdx.x & 63) >= off) v += u;
    }
    return v;
}

// exclusive block scan; wsum must hold >= nw ints; nw = blockDim/64
__device__ inline int block_excl_scan(int v, int* wsum, int nw) {
    int t = threadIdx.x, wid = t >> 6, lane = t & 63;
    int incl = wave_incl_scan(v);
    if (lane == 63) wsum[wid] = incl;
    __syncthreads();
    if (wid == 0) {
        int wv = (lane < nw) ? wsum[lane] : 0;
        wv = wave_incl_scan(wv);
        if (lane < nw) wsum[lane] = wv;
    }
    __syncthreads();
    return incl - v + (wid ? wsum[wid - 1] : 0);
}

// ---------------- CSR build: radix partition + per-partition sort ----------------

// Pass 1: per-block LDS histogram over 391 dst-partitions.
__global__ __launch_bounds__(1024) void k_hist(const int* __restrict__ dstA, int* __restrict__ bh) {
    __shared__ int h[NPART];
    int t = threadIdx.x;
    for (int i = t; i < NPART; i += 1024) h[i] = 0;
    __syncthreads();
    int base = blockIdx.x * CHUNK;
#pragma unroll
    for (int k = 0; k < CHUNK / 1024; k++) {
        int e = base + k * 1024 + t;
        if (e < ET) {
            int d = (e < NE) ? dstA[e] : (e - NE);   // virtual self-loop edges
            atomicAdd(&h[d >> PSHIFT], 1);
        }
    }
    __syncthreads();
    for (int i = t; i < NPART; i += 1024) bh[i * NBLK + blockIdx.x] = h[i];  // column-major
}

// Pass 2a: per-partition totals (391 blocks, parallel).
__global__ __launch_bounds__(256) void k_psum(const int* __restrict__ bh, int* __restrict__ psum) {
    __shared__ int wsum[4];
    int p = blockIdx.x, t = threadIdx.x;
    int v = (t < NBLK) ? bh[p * NBLK + t] : 0;
#pragma unroll
    for (int off = 32; off > 0; off >>= 1) v += __shfl_xor(v, off);
    if ((t & 63) == 0) wsum[t >> 6] = v;
    __syncthreads();
    if (t == 0) psum[p] = wsum[0] + wsum[1] + wsum[2] + wsum[3];
}

// Pass 2b: exclusive scan of the 391 partition totals (1 small block).
__global__ __launch_bounds__(512) void k_pbase(const int* __restrict__ psum, int* __restrict__ pbase,
                                               int* __restrict__ rowstart) {
    __shared__ int wsum[8];
    int t = threadIdx.x;
    int v = (t < NPART) ? psum[t] : 0;
    int excl = block_excl_scan(v, wsum, 8);
    if (t < NPART) pbase[t] = excl;
    if (t == 0) rowstart[NN] = ET;
}

// Pass 2c: per-partition exclusive scan over its 208 block-counts + add base (391 blocks).
__global__ __launch_bounds__(256) void k_pscan2(int* __restrict__ bh, const int* __restrict__ pbase) {
    __shared__ int wsum[4];
    int p = blockIdx.x, t = threadIdx.x;
    int v = (t < NBLK) ? bh[p * NBLK + t] : 0;
    int excl = block_excl_scan(v, wsum, 4);
    if (t < NBLK) bh[p * NBLK + t] = pbase[p] + excl;
}

// Pass 3: scatter packed (dloc<<17)|src into partition-ordered buffer.
// LDS cursors seeded from the scan -> pre-reserved slots; NO global atomics.
__global__ __launch_bounds__(1024) void k_part(const int* __restrict__ srcA, const int* __restrict__ dstA,
                                               const int* __restrict__ bh, int* __restrict__ pairs) {
    __shared__ int cur[NPART];
    int t = threadIdx.x;
    for (int i = t; i < NPART; i += 1024) cur[i] = bh[i * NBLK + blockIdx.x];
    __syncthreads();
    int base = blockIdx.x * CHUNK;
#pragma unroll
    for (int k = 0; k < CHUNK / 1024; k++) {
        int e = base + k * 1024 + t;
        if (e < ET) {
            int s, d;
            if (e < NE) { s = srcA[e]; d = dstA[e]; }
            else        { s = e - NE;  d = s; }
            int pos = atomicAdd(&cur[d >> PSHIFT], 1);   // LDS atomic
            pairs[pos] = ((d & (PARTW - 1)) << 17) | s;  // src < 2^17, dloc < 2^8
        }
    }
}

// Pass 4: one block per partition: LDS counting sort of <=256 local nodes.
__global__ __launch_bounds__(1024) void k_sort(const int* __restrict__ bh, const int* __restrict__ pairs,
                                               int* __restrict__ rowstart, int* __restrict__ esrc) {
    __shared__ int hist[PARTW];
    __shared__ int sa[PARTW], sb[PARTW];
    int p = blockIdx.x;
    int t = threadIdx.x;
    int n0 = p << PSHIFT;
    int nn = min(PARTW, NN - n0);
    int base = bh[p * NBLK];
    int endp = (p == NPART - 1) ? ET : bh[(p + 1) * NBLK];
    int cnt = endp - base;
    if (t < PARTW) hist[t] = 0;
    __syncthreads();
    for (int i = t; i < cnt; i += 1024)
        atomicAdd(&hist[pairs[base + i] >> 17], 1);
    __syncthreads();
    if (t < PARTW) sa[t] = hist[t];
    __syncthreads();
    int* pin = sa; int* pout = sb;
    for (int off = 1; off < PARTW; off <<= 1) {
        if (t < PARTW) pout[t] = pin[t] + ((t >= off) ? pin[t - off] : 0);
        __syncthreads();
        int* tmp = pin; pin = pout; pout = tmp;
    }
    int excl = 0;
    if (t < PARTW) {
        excl = pin[t] - hist[t];
        if (t < nn) rowstart[n0 + t] = base + excl;
    }
    __syncthreads();
    if (t < PARTW) hist[t] = excl;   // reuse as cursor
    __syncthreads();
    for (int i = t; i < cnt; i += 1024) {
        int v = pairs[base + i];
        int pos = base + atomicAdd(&hist[v >> 17], 1);  // LDS atomic
        esrc[pos] = v & 0x1FFFF;
    }
}

// ---------------- Layer 1: x@W1 + attention coefficients (xw1 stored fp16) ----------------

__global__ __launch_bounds__(256) void k_gemm1(const float* __restrict__ x, const float* __restrict__ W1,
        const float* __restrict__ a1s, const float* __restrict__ a1d,
        _Float16* __restrict__ xw1h, float* __restrict__ as1, float* __restrict__ ad1) {
    int n = blockIdx.x * 256 + threadIdx.x;
    if (n >= NN) return;
    float acc[F1];
#pragma unroll
    for (int c = 0; c < F1; c++) acc[c] = 0.f;
    const float4* x4 = (const float4*)(x + (size_t)n * FIN);
#pragma unroll 4
    for (int k4 = 0; k4 < FIN / 4; k4++) {
        float4 xv = x4[k4];
        float xk[4] = {xv.x, xv.y, xv.z, xv.w};
#pragma unroll
        for (int kk = 0; kk < 4; kk++) {
            int k = k4 * 4 + kk;
#pragma unroll
            for (int c = 0; c < F1; c++)
                acc[c] = fmaf(xk[kk], W1[k * F1 + c], acc[c]);  // W1 addr wave-uniform -> s_load
        }
    }
    half8* o8 = (half8*)(xw1h + (size_t)n * F1);
#pragma unroll
    for (int c8 = 0; c8 < F1 / 8; c8++) {
        half8 o;
#pragma unroll
        for (int k = 0; k < 8; k++) o[k] = (_Float16)acc[c8 * 8 + k];
        o8[c8] = o;
    }
#pragma unroll
    for (int h = 0; h < H1; h++) {
        float ss = 0.f, dd = 0.f;
#pragma unroll
        for (int c = 0; c < C1; c++) {
            ss = fmaf(acc[h*C1+c], a1s[h*C1+c], ss);
            dd = fmaf(acc[h*C1+c], a1d[h*C1+c], dd);
        }
        as1[n*H1+h] = ss;
        ad1[n*H1+h] = dd;
    }
}

// ---------------- Layer 1 gather: softmax-aggregate + bias + ELU -> h1 (fp16) ----------------
// 64 lanes per node (1 wave/node). Halves process interleaved edges, unroll x4
// -> 8 independent gathers in flight per wave.

__global__ __launch_bounds__(256) void k_gather1(const int* __restrict__ rowstart, const int* __restrict__ esrc,
        const float* __restrict__ as1, const float* __restrict__ ad1,
        const _Float16* __restrict__ xw1h, const float* __restrict__ b1,
        _Float16* __restrict__ h1h) {
    int n = blockIdx.x * 4 + (threadIdx.x >> 6);
    if (n >= NN) return;
    int l = threadIdx.x & 63;
    int c = l & 31;
    int h = c >> 3;
    int half = l >> 5;
    float adh = ad1[n * H1 + h];
    int beg = rowstart[n], end = rowstart[n + 1];
    float accn = 0.f, accd = 0.f;
    int i = beg + half;
    for (; i + 6 < end; i += 8) {
        int s0 = esrc[i], s1 = esrc[i + 2], s2 = esrc[i + 4], s3 = esrc[i + 6];
        float e0 = as1[s0 * H1 + h] + adh;
        float e1 = as1[s1 * H1 + h] + adh;
        float e2 = as1[s2 * H1 + h] + adh;
        float e3 = as1[s3 * H1 + h] + adh;
        float x0 = (float)xw1h[s0 * F1 + c];
        float x1 = (float)xw1h[s1 * F1 + c];
        float x2 = (float)xw1h[s2 * F1 + c];
        float x3 = (float)xw1h[s3 * F1 + c];
        e0 = (e0 > 0.f) ? e0 : NSLOPE * e0;
        e1 = (e1 > 0.f) ? e1 : NSLOPE * e1;
        e2 = (e2 > 0.f) ? e2 : NSLOPE * e2;
        e3 = (e3 > 0.f) ? e3 : NSLOPE * e3;
        float ee0 = __expf(e0), ee1 = __expf(e1), ee2 = __expf(e2), ee3 = __expf(e3);
        accd += (ee0 + ee1) + (ee2 + ee3);
        accn = fmaf(ee0, x0, fmaf(ee1, x1, fmaf(ee2, x2, fmaf(ee3, x3, accn))));
    }
    for (; i < end; i += 2) {
        int s0 = esrc[i];
        float e0 = as1[s0 * H1 + h] + adh;
        float x0 = (float)xw1h[s0 * F1 + c];
        e0 = (e0 > 0.f) ? e0 : NSLOPE * e0;
        float ee0 = __expf(e0);
        accd += ee0;
        accn = fmaf(ee0, x0, accn);
    }
    accn += __shfl_xor(accn, 32);
    accd += __shfl_xor(accd, 32);
    float y = accn / accd + b1[c];
    y = (y > 0.f) ? y : expm1f(y);   // ELU
    if (l < 32) h1h[(size_t)n * F1 + c] = (_Float16)y;
}

// ---------------- Layer 2 node transform: h1@W2 + attention coefficients ----------------

__global__ __launch_bounds__(256) void k_node2(const _Float16* __restrict__ h1h, const float* __restrict__ W2,
        const float* __restrict__ a2s, const float* __restrict__ a2d,
        _Float16* __restrict__ xw2h, float* __restrict__ as2, float* __restrict__ ad2) {
    int n = blockIdx.x * 256 + threadIdx.x;
    if (n >= NN) return;
    float acc[FOUT];
#pragma unroll
    for (int j = 0; j < FOUT; j++) acc[j] = 0.f;
    const half8* h8 = (const half8*)(h1h + (size_t)n * F1);
#pragma unroll
    for (int i8 = 0; i8 < F1 / 8; i8++) {
        half8 hv = h8[i8];
#pragma unroll
        for (int kk = 0; kk < 8; kk++) {
            float hk = (float)hv[kk];
            int i = i8 * 8 + kk;
#pragma unroll
            for (int j = 0; j < FOUT; j++)
                acc[j] = fmaf(hk, W2[i * FOUT + j], acc[j]);   // wave-uniform -> scalar
        }
    }
    float ss = 0.f, dd = 0.f;
#pragma unroll
    for (int j = 0; j < FOUT; j++) {
        ss = fmaf(acc[j], a2s[j], ss);
        dd = fmaf(acc[j], a2d[j], dd);
    }
    half8* o8 = (half8*)(xw2h + (size_t)n * FOUT);
#pragma unroll
    for (int j8 = 0; j8 < FOUT / 8; j8++) {
        half8 o;
#pragma unroll
        for (int k = 0; k < 8; k++) o[k] = (_Float16)acc[j8 * 8 + k];
        o8[j8] = o;
    }
    as2[n] = ss;
    ad2[n] = dd;
}

// ---------------- Layer 2: gather softmax-aggregate + bias + log_softmax ----------------
// 64 lanes per node: quarters process interleaved edges, unroll x4 -> 16 in flight.

__global__ __launch_bounds__(256) void k_gather2(const int* __restrict__ rowstart, const int* __restrict__ esrc,
        const float* __restrict__ as2, const float* __restrict__ ad2,
        const _Float16* __restrict__ xw2h, const float* __restrict__ b2,
        float* __restrict__ out) {
    int n = blockIdx.x * 4 + (threadIdx.x >> 6);
    if (n >= NN) return;
    int l = threadIdx.x & 63;
    int c = l & 15;
    int q = l >> 4;
    float adn = ad2[n];
    int beg = rowstart[n], end = rowstart[n + 1];
    float accn = 0.f, accd = 0.f;
    int i = beg + q;
    for (; i + 12 < end; i += 16) {
        int s0 = esrc[i], s1 = esrc[i + 4], s2 = esrc[i + 8], s3 = esrc[i + 12];
        float e0 = as2[s0] + adn;
        float e1 = as2[s1] + adn;
        float e2 = as2[s2] + adn;
        float e3 = as2[s3] + adn;
        float x0 = (float)xw2h[s0 * FOUT + c];
        float x1 = (float)xw2h[s1 * FOUT + c];
        float x2 = (float)xw2h[s2 * FOUT + c];
        float x3 = (float)xw2h[s3 * FOUT + c];
        e0 = (e0 > 0.f) ? e0 : NSLOPE * e0;
        e1 = (e1 > 0.f) ? e1 : NSLOPE * e1;
        e2 = (e2 > 0.f) ? e2 : NSLOPE * e2;
        e3 = (e3 > 0.f) ? e3 : NSLOPE * e3;
        float ee0 = __expf(e0), ee1 = __expf(e1), ee2 = __expf(e2), ee3 = __expf(e3);
        accd += (ee0 + ee1) + (ee2 + ee3);
        accn = fmaf(ee0, x0, fmaf(ee1, x1, fmaf(ee2, x2, fmaf(ee3, x3, accn))));
    }
    for (; i < end; i += 4) {
        int s0 = esrc[i];
        float e0 = as2[s0] + adn;
        float x0 = (float)xw2h[s0 * FOUT + c];
        e0 = (e0 > 0.f) ? e0 : NSLOPE * e0;
        float ee0 = __expf(e0);
        accd += ee0;
        accn = fmaf(ee0, x0, accn);
    }
    accn += __shfl_xor(accn, 16);
    accn += __shfl_xor(accn, 32);
    accd += __shfl_xor(accd, 16);
    accd += __shfl_xor(accd, 32);
    float y = accn / accd + b2[c];
    float m = y;
#pragma unroll
    for (int off = 8; off > 0; off >>= 1) m = fmaxf(m, __shfl_xor(m, off));
    float ex = __expf(y - m);
    float sum = ex;
#pragma unroll
    for (int off = 8; off > 0; off >>= 1) sum += __shfl_xor(sum, off);
    if (l < 16) out[(size_t)n * FOUT + c] = y - m - logf(sum);
}

// ---------------- launch ----------------

extern "C" void kernel_launch(void* const* d_in, const int* in_sizes, int n_in,
                              void* d_out, int out_size, void* d_ws, size_t ws_size,
                              hipStream_t stream) {
    const float* x   = (const float*)d_in[0];
    const int*   ei  = (const int*)d_in[1];
    const float* W1  = (const float*)d_in[2];
    const float* a1s = (const float*)d_in[3];
    const float* a1d = (const float*)d_in[4];
    const float* b1  = (const float*)d_in[5];
    const float* W2  = (const float*)d_in[6];
    const float* a2s = (const float*)d_in[7];
    const float* a2d = (const float*)d_in[8];
    const float* b2  = (const float*)d_in[9];
    float* out = (float*)d_out;

    const int* srcA = ei;        // edge_index[0]
    const int* dstA = ei + NE;   // edge_index[1]

    char* w = (char*)d_ws;
    size_t off = 0;
    auto carve = [&](size_t bytes) -> void* {
        void* p = w + off;
        off = (off + bytes + 255) & ~(size_t)255;
        return p;
    };
    _Float16* xw1h = (_Float16*)carve((size_t)NN * F1 * 2);   // 6.4 MB
    float* as1     = (float*)carve((size_t)NN * H1 * 4);      // 1.6 MB
    float* ad1     = (float*)carve((size_t)NN * H1 * 4);      // 1.6 MB
    _Float16* h1h  = (_Float16*)carve((size_t)NN * F1 * 2);   // 6.4 MB
    _Float16* xw2h = (_Float16*)carve((size_t)NN * FOUT * 2); // 3.2 MB
    float* as2     = (float*)carve((size_t)NN * 4);
    float* ad2     = (float*)carve((size_t)NN * 4);
    int* rowstart  = (int*)carve((size_t)(NN + 1) * 4);
    int* esrc      = (int*)carve((size_t)ET * 4);             // 6.8 MB
    int* pairs     = (int*)carve((size_t)ET * 4);             // 6.8 MB
    int* bh        = (int*)carve((size_t)MTOT * 4);           // 325 KB
    int* psum      = (int*)carve((size_t)NPART * 4);
    int* pbase     = (int*)carve((size_t)NPART * 4);
    (void)ws_size; (void)in_sizes; (void)n_in; (void)out_size;

    k_hist  <<<NBLK, 1024, 0, stream>>>(dstA, bh);
    k_psum  <<<NPART, 256, 0, stream>>>(bh, psum);
    k_pbase <<<1, 512, 0, stream>>>(psum, pbase, rowstart);
    k_pscan2<<<NPART, 256, 0, stream>>>(bh, pbase);
    k_part  <<<NBLK, 1024, 0, stream>>>(srcA, dstA, bh, pairs);
    k_sort  <<<NPART, 1024, 0, stream>>>(bh, pairs, rowstart, esrc);

    k_gemm1  <<<(NN + 255) / 256, 256, 0, stream>>>(x, W1, a1s, a1d, xw1h, as1, ad1);
    k_gather1<<<(NN + 3) / 4, 256, 0, stream>>>(rowstart, esrc, as1, ad1, xw1h, b1, h1h);
    k_node2  <<<(NN + 255) / 256, 256, 0, stream>>>(h1h, W2, a2s, a2d, xw2h, as2, ad2);
    k_gather2<<<(NN + 3) / 4, 256, 0, stream>>>(rowstart, esrc, as2, ad2, xw2h, b2, out);
}